// Round 3
// baseline (11360.542 us; speedup 1.0000x reference)
//
#include <hip/hip_runtime.h>

// ---- static config ----
static constexpr int NN   = 128;   // dialogues
static constexpr int LL   = 64;    // utterance length
static constexpr int EE   = 300;   // embedding
static constexpr int KWIN = 40;
static constexpr int KEFF = 40;
static constexpr int NQ   = 127;   // N-1
static constexpr int NCLS = 6;

__device__ __forceinline__ float sigm(float x) { return 1.f / (1.f + __expf(-x)); }

// ---------------------------------------------------------------------------
// Gather x rows: A[r=t*128+n][0..299] = emb[ids[n*64+t]]
// ---------------------------------------------------------------------------
__global__ void k_gather_x(const float* __restrict__ emb,
                           const int* __restrict__ ids,
                           float* __restrict__ A)
{
    int r = blockIdx.x;            // t*128 + n
    int n = r & (NN - 1);
    int t = r >> 7;
    int id = ids[n * LL + t];
    const float* src = emb + (size_t)id * EE;
    float* dst = A + (size_t)r * EE;
    for (int e = threadIdx.x; e < EE; e += blockDim.x) dst[e] = src[e];
}

// ---------------------------------------------------------------------------
// f32 GEMM: C[r,c] = act( sum_k A[r,k]*B[c,k] + bias[c] )
// 128x128 tile, 8x8 micro, KT=16.
// ---------------------------------------------------------------------------
__global__ __launch_bounds__(256)
void k_gemm(const float* __restrict__ A,
            const float* __restrict__ B,
            const float* __restrict__ bias,
            float* __restrict__ C,
            int R, int Cc, int K, int actTanh)
{
    __shared__ __align__(16) float As[16][132];
    __shared__ __align__(16) float Bs[16][132];
    const int tid = threadIdx.x;
    const int r0 = blockIdx.y * 128;
    const int c0 = blockIdx.x * 128;
    const int li = tid >> 1;
    const int lk = (tid & 1) * 8;
    const int tx = tid & 15, ty = tid >> 4;
    float acc[8][8];
#pragma unroll
    for (int i = 0; i < 8; ++i)
#pragma unroll
        for (int j = 0; j < 8; ++j) acc[i][j] = 0.f;
    const int nch = (K + 15) >> 4;
    for (int ch = 0; ch < nch; ++ch) {
        const int k0 = ch * 16;
        {   // A tile
            float v[8];
            int gr = r0 + li;
            int kb = k0 + lk;
            if (gr < R && kb + 8 <= K) {
                const float* p = A + (size_t)gr * K + kb;
                *(float4*)&v[0] = *(const float4*)p;
                *(float4*)&v[4] = *(const float4*)(p + 4);
            } else {
#pragma unroll
                for (int z = 0; z < 8; ++z) {
                    int k = kb + z;
                    v[z] = (gr < R && k < K) ? A[(size_t)gr * K + k] : 0.f;
                }
            }
#pragma unroll
            for (int z = 0; z < 8; ++z) As[lk + z][li] = v[z];
        }
        {   // B tile
            float v[8];
            int gr = c0 + li;
            int kb = k0 + lk;
            if (gr < Cc && kb + 8 <= K) {
                const float* p = B + (size_t)gr * K + kb;
                *(float4*)&v[0] = *(const float4*)p;
                *(float4*)&v[4] = *(const float4*)(p + 4);
            } else {
#pragma unroll
                for (int z = 0; z < 8; ++z) {
                    int k = kb + z;
                    v[z] = (gr < Cc && k < K) ? B[(size_t)gr * K + k] : 0.f;
                }
            }
#pragma unroll
            for (int z = 0; z < 8; ++z) Bs[lk + z][li] = v[z];
        }
        __syncthreads();
#pragma unroll
        for (int kk = 0; kk < 16; ++kk) {
            float a[8], b[8];
            *(float4*)&a[0] = *(const float4*)&As[kk][ty * 8];
            *(float4*)&a[4] = *(const float4*)&As[kk][ty * 8 + 4];
            *(float4*)&b[0] = *(const float4*)&Bs[kk][tx * 8];
            *(float4*)&b[4] = *(const float4*)&Bs[kk][tx * 8 + 4];
#pragma unroll
            for (int i = 0; i < 8; ++i)
#pragma unroll
                for (int j = 0; j < 8; ++j) acc[i][j] = fmaf(a[i], b[j], acc[i][j]);
        }
        __syncthreads();
    }
#pragma unroll
    for (int i = 0; i < 8; ++i) {
        int r = r0 + ty * 8 + i;
        if (r >= R) continue;
#pragma unroll
        for (int j = 0; j < 8; ++j) {
            int c = c0 + tx * 8 + j;
            if (c >= Cc) continue;
            float v = acc[i][j];
            if (bias) v += bias[c];
            if (actTanh) v = tanhf(v);
            C[(size_t)r * Cc + c] = v;
        }
    }
}

// ---------------------------------------------------------------------------
// Utterance BiGRU scan, weight-stationary: one block = 1 (sample, dir) chain.
// Thread a<900 holds Whh row a (75 float4 = 300 VGPRs); h broadcast from LDS.
// gi: [L*128][1800] f32 (row t*128+n, col d*900+{j,j+300,j+600}), includes bih.
// maxpool: [128][600] f32 (cols: fwd 0..299, bwd 300..599)
// ---------------------------------------------------------------------------
__global__ __launch_bounds__(960, 1)
void k_utt_scan(const float* __restrict__ Whh,
                const float* __restrict__ bhh,
                const float* __restrict__ gi,
                const int* __restrict__ lens,
                float* __restrict__ maxpool)
{
    const int d = blockIdx.y;
    const int n = blockIdx.x;
    const int tid = threadIdx.x;
    __shared__ __align__(16) float hs[304];
    __shared__ __align__(16) float ds[904];
    if (tid < 300) hs[tid] = 0.f;
    const int len = lens[n];
    float4 w[75];
    if (tid < 900) {
        const float4* wrow = (const float4*)(Whh + ((size_t)d * 900 + tid) * 300);
#pragma unroll
        for (int c = 0; c < 75; ++c) w[c] = wrow[c];
    }
    float br = 0.f, bz = 0.f, bn = 0.f;
    if (tid < 300) {
        br = bhh[d * 900 + tid];
        bz = bhh[d * 900 + 300 + tid];
        bn = bhh[d * 900 + 600 + tid];
    }
    float m = -1e30f;
    __syncthreads();
    for (int t = 0; t < len; ++t) {       // len is block-uniform
        if (tid < 900) {
            float d0 = 0.f, d1 = 0.f, d2 = 0.f, d3 = 0.f;
            const float4* h4 = (const float4*)hs;
#pragma unroll
            for (int c = 0; c < 75; ++c) {
                float4 hv = h4[c];
                d0 = fmaf(w[c].x, hv.x, d0);
                d1 = fmaf(w[c].y, hv.y, d1);
                d2 = fmaf(w[c].z, hv.z, d2);
                d3 = fmaf(w[c].w, hv.w, d3);
            }
            ds[tid] = (d0 + d1) + (d2 + d3);
        }
        __syncthreads();
        if (tid < 300) {
            int ts = d ? (len - 1 - t) : t;
            size_t row = ((size_t)(ts * NN + n)) * 1800 + d * 900 + tid;
            float r = sigm(gi[row] + ds[tid] + br);
            float z = sigm(gi[row + 300] + ds[tid + 300] + bz);
            float nv = tanhf(gi[row + 600] + r * (ds[tid + 600] + bn));
            float hv = (1.f - z) * nv + z * hs[tid];
            hs[tid] = hv;
            m = fmaxf(m, hv);
        }
        __syncthreads();
    }
    if (tid < 300) {
        if (len < LL) m = fmaxf(m, 0.f);   // padded steps contribute 0 to the max
        maxpool[(size_t)n * 600 + d * 300 + tid] = m;
    }
}

// ---------------------------------------------------------------------------
// query init, ctx A build
// ---------------------------------------------------------------------------
__global__ void k_init_query(const float* __restrict__ u, float* __restrict__ query)
{
    int q = blockIdx.x;
    for (int e = threadIdx.x; e < 300; e += blockDim.x)
        query[(size_t)q * 300 + e] = u[(size_t)(q + 1) * 300 + e];
}

__global__ void k_build_ctxA(const float* __restrict__ u, float* __restrict__ Actx)
{
    int rkq = blockIdx.x;            // k*127 + q
    int k = rkq / NQ, q = rkq - k * NQ;
    int src = q + 1 - KWIN + k;
    for (int e = threadIdx.x; e < 300; e += blockDim.x)
        Actx[(size_t)rkq * 300 + e] = (src >= 0) ? u[(size_t)src * 300 + e] : 0.f;
}

// ---------------------------------------------------------------------------
// Context BiGRU scan, weight-stationary. One block = 1 (q, dir) chain.
// Writes hout[d][q][slot][300].
// ---------------------------------------------------------------------------
__global__ __launch_bounds__(960, 1)
void k_ctx_scan(const float* __restrict__ Whh,
                const float* __restrict__ bhh,
                const float* __restrict__ gi,   // [40*127][1800]
                float* __restrict__ hout)        // [2][127][40][300]
{
    const int d = blockIdx.y;
    const int q = blockIdx.x;
    const int tid = threadIdx.x;
    __shared__ __align__(16) float hs[304];
    __shared__ __align__(16) float ds[904];
    if (tid < 300) hs[tid] = 0.f;
    float4 w[75];
    if (tid < 900) {
        const float4* wrow = (const float4*)(Whh + ((size_t)d * 900 + tid) * 300);
#pragma unroll
        for (int c = 0; c < 75; ++c) w[c] = wrow[c];
    }
    float br = 0.f, bz = 0.f, bn = 0.f;
    if (tid < 300) {
        br = bhh[d * 900 + tid];
        bz = bhh[d * 900 + 300 + tid];
        bn = bhh[d * 900 + 600 + tid];
    }
    __syncthreads();
    for (int t = 0; t < KEFF; ++t) {
        if (tid < 900) {
            float d0 = 0.f, d1 = 0.f, d2 = 0.f, d3 = 0.f;
            const float4* h4 = (const float4*)hs;
#pragma unroll
            for (int c = 0; c < 75; ++c) {
                float4 hv = h4[c];
                d0 = fmaf(w[c].x, hv.x, d0);
                d1 = fmaf(w[c].y, hv.y, d1);
                d2 = fmaf(w[c].z, hv.z, d2);
                d3 = fmaf(w[c].w, hv.w, d3);
            }
            ds[tid] = (d0 + d1) + (d2 + d3);
        }
        __syncthreads();
        if (tid < 300) {
            int ts = d ? (KEFF - 1 - t) : t;
            size_t row = ((size_t)(ts * NQ + q)) * 1800 + d * 900 + tid;
            float r = sigm(gi[row] + ds[tid] + br);
            float z = sigm(gi[row + 300] + ds[tid + 300] + bz);
            float nv = tanhf(gi[row + 600] + r * (ds[tid + 600] + bn));
            float hv = (1.f - z) * nv + z * hs[tid];
            hs[tid] = hv;
            hout[(((size_t)d * NQ + q) * KEFF + ts) * 300 + tid] = hv;
        }
        __syncthreads();
    }
}

// ---------------------------------------------------------------------------
// mem_bank[q][k][j] = ctx + h_f + h_b ; also copy in (k*127+q) row order
// ---------------------------------------------------------------------------
__global__ void k_combine(const float* __restrict__ u, const float* __restrict__ hout,
                          float* __restrict__ mem_bank, float* __restrict__ mrkq)
{
    int rkq = blockIdx.x;            // k*127 + q
    int k = rkq / NQ, q = rkq - k * NQ;
    int src = q + 1 - KWIN + k;
    for (int e = threadIdx.x; e < 300; e += blockDim.x) {
        float c = (src >= 0) ? u[(size_t)src * 300 + e] : 0.f;
        float v = c + hout[((size_t)q * KEFF + k) * 300 + e]
                    + hout[(((size_t)NQ + q) * KEFF + k) * 300 + e];
        mem_bank[((size_t)q * KEFF + k) * 300 + e] = v;
        mrkq[(size_t)rkq * 300 + e] = v;
    }
}

// ---------------------------------------------------------------------------
// scores[q][k] = softmax_k( query[q]·mem_bank[q][k], masked k < 39-q )
// ---------------------------------------------------------------------------
__global__ __launch_bounds__(64)
void k_score(const float* __restrict__ query, const float* __restrict__ mem_bank,
             float* __restrict__ scores)
{
    const int q = blockIdx.x;
    __shared__ float qv[300];
    for (int e = threadIdx.x; e < 300; e += 64) qv[e] = query[(size_t)q * 300 + e];
    __syncthreads();
    int k = threadIdx.x;
    float s = -1e30f;
    if (k < KEFF) {
        const float* m = mem_bank + ((size_t)q * KEFF + k) * 300;
        float acc = 0.f;
        for (int e = 0; e < 300; ++e) acc = fmaf(qv[e], m[e], acc);
        s = (k < KWIN - 1 - q) ? -1e10f : acc;
    }
    float mx = s;
    for (int o = 32; o > 0; o >>= 1) mx = fmaxf(mx, __shfl_xor(mx, o));
    float e = (k < KEFF) ? __expf(s - mx) : 0.f;
    float sm = e;
    for (int o = 32; o > 0; o >>= 1) sm += __shfl_xor(sm, o);
    if (k < KEFF) scores[q * KEFF + k] = e / sm;
}

// ---------------------------------------------------------------------------
// AttnGRU scan, weight-stationary: one block = 1 (q, dir); thread a<300 holds
// Ur row a, thread 300<=a<600 holds Uw row a-300.
// ---------------------------------------------------------------------------
__global__ __launch_bounds__(640, 1)
void k_att_scan(const float* __restrict__ Urw,   // [6*300][300]
                const float* __restrict__ Uww,
                const float* __restrict__ burb,  // [6*300]
                const float* __restrict__ bub,
                const float* __restrict__ xgr,   // [5080][1800]
                const float* __restrict__ xgw,
                const float* __restrict__ scores, // [127][40]
                float* __restrict__ hbuf,         // [2][127][300]
                int hop)
{
    const int d = blockIdx.y;
    const int q = blockIdx.x;
    const int tid = threadIdx.x;
    const int hd = hop * 2 + d;
    __shared__ __align__(16) float hs[304];
    __shared__ __align__(16) float ds[600];
    if (tid < 300) hs[tid] = 0.f;
    float4 w[75];
    if (tid < 600) {
        const float* rowp = (tid < 300)
            ? (Urw + ((size_t)hd * 300 + tid) * 300)
            : (Uww + ((size_t)hd * 300 + (tid - 300)) * 300);
        const float4* w4 = (const float4*)rowp;
#pragma unroll
        for (int c = 0; c < 75; ++c) w[c] = w4[c];
    }
    float bur = 0.f, bu = 0.f;
    if (tid < 300) { bur = burb[hd * 300 + tid]; bu = bub[hd * 300 + tid]; }
    __syncthreads();
    for (int t = 0; t < KEFF; ++t) {
        if (tid < 600) {
            float d0 = 0.f, d1 = 0.f, d2 = 0.f, d3 = 0.f;
            const float4* h4 = (const float4*)hs;
#pragma unroll
            for (int c = 0; c < 75; ++c) {
                float4 hv = h4[c];
                d0 = fmaf(w[c].x, hv.x, d0);
                d1 = fmaf(w[c].y, hv.y, d1);
                d2 = fmaf(w[c].z, hv.z, d2);
                d3 = fmaf(w[c].w, hv.w, d3);
            }
            ds[tid] = (d0 + d1) + (d2 + d3);
        }
        __syncthreads();
        if (tid < 300) {
            int kq = d ? (KEFF - 1 - t) : t;
            float gt = scores[q * KEFF + kq];
            size_t xi = ((size_t)(kq * NQ + q)) * 1800 + (size_t)hd * 300 + tid;
            float r = sigm(xgr[xi] + ds[tid] + bur);
            float ht = tanhf(xgw[xi] + r * (ds[tid + 300] + bu));
            hs[tid] = gt * ht + (1.f - gt) * hs[tid];
        }
        __syncthreads();
    }
    if (tid < 300)
        hbuf[((size_t)d * NQ + q) * 300 + tid] = hs[tid];
}

__global__ void k_qupd(float* __restrict__ query, const float* __restrict__ hbuf)
{
    int q = blockIdx.x;
    for (int e = threadIdx.x; e < 300; e += blockDim.x)
        query[(size_t)q * 300 + e] += hbuf[(size_t)q * 300 + e]
                                    + hbuf[(size_t)(NQ + q) * 300 + e];
}

// ---------------------------------------------------------------------------
// classifier: out[n][c] = s_context[n]·cls_w[c] + cls_b[c]
// ---------------------------------------------------------------------------
__global__ __launch_bounds__(64)
void k_cls(const float* __restrict__ u, const float* __restrict__ query,
           const float* __restrict__ cw, const float* __restrict__ cb,
           float* __restrict__ out)
{
    int n = blockIdx.x;
    const float* srow = (n == 0) ? u : (query + (size_t)(n - 1) * 300);
    int c = threadIdx.x & 7;
    int part = threadIdx.x >> 3;
    float p = 0.f;
    if (c < NCLS) {
        for (int e = part; e < 300; e += 8) p = fmaf(srow[e], cw[c * 300 + e], p);
    }
    p += __shfl_xor(p, 8);
    p += __shfl_xor(p, 16);
    p += __shfl_xor(p, 32);
    if (part == 0 && c < NCLS) out[n * NCLS + c] = p + cb[c];
}

// ---------------------------------------------------------------------------
extern "C" void kernel_launch(void* const* d_in, const int* in_sizes, int n_in,
                              void* d_out, int out_size, void* d_ws, size_t ws_size,
                              hipStream_t stream)
{
    const int* ids  = (const int*)d_in[0];
    const int* lens = (const int*)d_in[1];
    const float* emb   = (const float*)d_in[2];
    const float* uWih  = (const float*)d_in[3];
    const float* uWhh  = (const float*)d_in[4];
    const float* ubih  = (const float*)d_in[5];
    const float* ubhh  = (const float*)d_in[6];
    const float* linw  = (const float*)d_in[7];
    const float* linb  = (const float*)d_in[8];
    const float* cWih  = (const float*)d_in[9];
    const float* cWhh  = (const float*)d_in[10];
    const float* cbih  = (const float*)d_in[11];
    const float* cbhh  = (const float*)d_in[12];
    const float* aWr_w = (const float*)d_in[13];
    const float* aWr_b = (const float*)d_in[14];
    const float* aUr_w = (const float*)d_in[15];
    const float* aUr_b = (const float*)d_in[16];
    const float* aW_w  = (const float*)d_in[17];
    const float* aW_b  = (const float*)d_in[18];
    const float* aU_w  = (const float*)d_in[19];
    const float* aU_b  = (const float*)d_in[20];
    const float* clsw  = (const float*)d_in[21];
    const float* clsb  = (const float*)d_in[22];
    float* out = (float*)d_out;
    (void)in_sizes; (void)n_in; (void)out_size; (void)ws_size;

    // ---- workspace layout (region1 reused: {Autt,giU} then {Actx,giC,hout})
    char* base = (char*)d_ws;
    float* Autt = (float*)base;                             //  9,830,400 B
    float* giU  = (float*)(base + 9830400);                 // 58,982,400 B -> ends 68,812,800
    float* Actx = (float*)base;                             //  6,096,000 B
    float* giC  = (float*)(base + 6096128);                 // 36,576,000 B -> ends 42,672,128
    float* hout = (float*)(base + 6096128 + 36576000);      // 12,192,000 B -> ends 54,864,128
    char* p2 = base + 68812800;
    size_t off = 0;
    auto alloc = [&](size_t b) -> void* {
        void* r = (void*)(p2 + off);
        off += (b + 255) & ~(size_t)255;
        return r;
    };
    float* mpool   = (float*)alloc((size_t)NN * 600 * 4);
    float* uu      = (float*)alloc((size_t)NN * 300 * 4);
    float* membank = (float*)alloc((size_t)NQ * KEFF * 300 * 4);   // [q][k][e]
    float* mrkq    = (float*)alloc((size_t)NQ * KEFF * 300 * 4);   // [k*127+q][e]
    float* xgr     = (float*)alloc((size_t)NQ * KEFF * 1800 * 4);
    float* xgw     = (float*)alloc((size_t)NQ * KEFF * 1800 * 4);
    float* query   = (float*)alloc((size_t)NQ * 300 * 4);
    float* scores  = (float*)alloc((size_t)NQ * KEFF * 4);
    float* hbuf    = (float*)alloc((size_t)2 * NQ * 300 * 4);

    const int RKQ = NQ * KEFF;  // 5080

    // 1) gather x rows, 2) utt input-gate GEMM, 3) utt BiGRU scan + maxpool
    k_gather_x<<<dim3(LL * NN), dim3(128), 0, stream>>>(emb, ids, Autt);
    k_gemm<<<dim3(15, 64), dim3(256), 0, stream>>>(Autt, uWih, ubih, giU,
                                                   LL * NN, 1800, 300, 0);
    k_utt_scan<<<dim3(NN, 2), dim3(960), 0, stream>>>(uWhh, ubhh, giU, lens, mpool);
    // 4) u = tanh(maxpool @ lin_w.T + lin_b)
    k_gemm<<<dim3(3, 1), dim3(256), 0, stream>>>(mpool, linw, linb, uu,
                                                 NN, 300, 600, 1);
    // 5) query init + ctx rows
    k_init_query<<<dim3(NQ), dim3(128), 0, stream>>>(uu, query);
    k_build_ctxA<<<dim3(RKQ), dim3(128), 0, stream>>>(uu, Actx);
    // 6) ctx input-gate GEMM + ctx BiGRU scan + combine
    k_gemm<<<dim3(15, 40), dim3(256), 0, stream>>>(Actx, cWih, cbih, giC,
                                                   RKQ, 1800, 300, 0);
    k_ctx_scan<<<dim3(NQ, 2), dim3(960), 0, stream>>>(cWhh, cbhh, giC, hout);
    k_combine<<<dim3(RKQ), dim3(128), 0, stream>>>(uu, hout, membank, mrkq);
    // 7) attention x-projections for all hops/dirs at once
    k_gemm<<<dim3(15, 40), dim3(256), 0, stream>>>(mrkq, aWr_w, aWr_b, xgr,
                                                   RKQ, 1800, 300, 0);
    k_gemm<<<dim3(15, 40), dim3(256), 0, stream>>>(mrkq, aW_w, aW_b, xgw,
                                                   RKQ, 1800, 300, 0);
    // 8) hops
    for (int hop = 0; hop < 3; ++hop) {
        k_score<<<dim3(NQ), dim3(64), 0, stream>>>(query, membank, scores);
        k_att_scan<<<dim3(NQ, 2), dim3(640), 0, stream>>>(aUr_w, aU_w, aUr_b, aU_b,
                                                          xgr, xgw, scores, hbuf, hop);
        k_qupd<<<dim3(NQ), dim3(128), 0, stream>>>(query, hbuf);
    }
    // 9) classifier
    k_cls<<<dim3(NN), dim3(64), 0, stream>>>(uu, query, clsw, clsb, out);
}

// Round 4
// 2708.892 us; speedup vs baseline: 4.1938x; 4.1938x over previous
//
#include <hip/hip_runtime.h>

// ---- static config ----
static constexpr int NN   = 128;   // dialogues
static constexpr int LL   = 64;    // utterance length
static constexpr int KWIN = 40;
static constexpr int KEFF = 40;
static constexpr int NQ   = 127;   // N-1
static constexpr int NCLS = 6;
static constexpr int KP   = 320;   // padded K for MFMA GEMMs (300 -> 320)
static constexpr int WS   = 304;   // padded row length for scan weights

typedef __attribute__((ext_vector_type(8))) short short8;
typedef __attribute__((ext_vector_type(4))) float floatx4;

__device__ __forceinline__ float sigm(float x) { return 1.f / (1.f + __expf(-x)); }
__device__ __forceinline__ short f2bf(float f) {
    unsigned x = __float_as_uint(f);
    unsigned r = (x + 0x7fffu + ((x >> 16) & 1u)) >> 16;
    return (short)r;
}
__device__ __forceinline__ void bfp(unsigned v, float& lo, float& hi) {
    lo = __uint_as_float(v << 16);
    hi = __uint_as_float(v & 0xffff0000u);
}

// ---------------------------------------------------------------------------
// Gather + convert: A[r=t*128+n][0..319] = bf16(emb[ids[n*64+t]]), zero-pad
// ---------------------------------------------------------------------------
__global__ void k_gather_bf16(const float* __restrict__ emb,
                              const int* __restrict__ ids,
                              short* __restrict__ A)
{
    int r = blockIdx.x;            // t*128 + n
    int n = r & (NN - 1);
    int t = r >> 7;
    int id = ids[n * LL + t];
    int e = threadIdx.x;           // 320 threads
    float v = (e < 300) ? emb[(size_t)id * 300 + e] : 0.f;
    A[(size_t)r * KP + e] = f2bf(v);
}

// f32 [rows][300] -> bf16 [rows][320], zero pad (GEMM operands)
__global__ void k_conv320(const float* __restrict__ src, short* __restrict__ dst)
{
    int r = blockIdx.x, e = threadIdx.x;   // 320 threads
    float v = (e < 300) ? src[(size_t)r * 300 + e] : 0.f;
    dst[(size_t)r * KP + e] = f2bf(v);
}

// f32 [rows][300] -> bf16 [rows][304], zero pad (scan weights)
__global__ void k_conv304(const float* __restrict__ src, short* __restrict__ dst)
{
    int r = blockIdx.x, e = threadIdx.x;   // 304 threads
    float v = (e < 300) ? src[(size_t)r * 300 + e] : 0.f;
    dst[(size_t)r * WS + e] = f2bf(v);
}

// build wAtt[hd][600][304]: rows 0..299 = Ur rows, 300..599 = Uw rows
__global__ void k_conv_att(const float* __restrict__ Ur, const float* __restrict__ Uw,
                           short* __restrict__ dst)
{
    int r = blockIdx.x;            // hd*600 + rr, grid 3600
    int hd = r / 600, rr = r - hd * 600;
    int e = threadIdx.x;           // 304 threads
    float v = 0.f;
    if (e < 300)
        v = (rr < 300) ? Ur[((size_t)hd * 300 + rr) * 300 + e]
                       : Uw[((size_t)hd * 300 + (rr - 300)) * 300 + e];
    dst[(size_t)r * WS + e] = f2bf(v);
}

// ---------------------------------------------------------------------------
// bf16 MFMA GEMM (B^T layout): C[r,c] = sum_k A[r,k]*B[c,k] + bias[c], f32 out
// A: [R][320] bf16, B: [Cc][320] bf16. 128x128 tile, 4 waves, 4x4 16x16x32.
// ---------------------------------------------------------------------------
__global__ __launch_bounds__(256)
void k_mgemm(const short* __restrict__ A, const short* __restrict__ B,
             const float* __restrict__ bias, float* __restrict__ C,
             int R, int Cc)
{
    __shared__ short As[128 * 40];   // row stride 40 shorts (80 B) vs bank conflicts
    __shared__ short Bs[128 * 40];
    const int tid = threadIdx.x;
    const int r0 = blockIdx.y * 128, c0 = blockIdx.x * 128;
    const int w = tid >> 6, lane = tid & 63;
    const int m16 = lane & 15, quad = lane >> 4;
    const int wm = w & 1, wn = w >> 1;
    floatx4 acc[4][4];
#pragma unroll
    for (int i = 0; i < 4; ++i)
#pragma unroll
        for (int j = 0; j < 4; ++j) acc[i][j] = (floatx4){0.f, 0.f, 0.f, 0.f};

    const int ra0 = tid >> 2,         sa0 = tid & 3;
    const int ra1 = (tid + 256) >> 2, sa1 = tid & 3;

    for (int k0 = 0; k0 < KP; k0 += 32) {
        short8 za = {0,0,0,0,0,0,0,0};
        short8 a0 = za, a1 = za, b0 = za, b1 = za;
        if (r0 + ra0 < R) a0 = *(const short8*)(A + (size_t)(r0 + ra0) * KP + k0 + sa0 * 8);
        if (r0 + ra1 < R) a1 = *(const short8*)(A + (size_t)(r0 + ra1) * KP + k0 + sa1 * 8);
        if (c0 + ra0 < Cc) b0 = *(const short8*)(B + (size_t)(c0 + ra0) * KP + k0 + sa0 * 8);
        if (c0 + ra1 < Cc) b1 = *(const short8*)(B + (size_t)(c0 + ra1) * KP + k0 + sa1 * 8);
        *(short8*)(As + ra0 * 40 + sa0 * 8) = a0;
        *(short8*)(As + ra1 * 40 + sa1 * 8) = a1;
        *(short8*)(Bs + ra0 * 40 + sa0 * 8) = b0;
        *(short8*)(Bs + ra1 * 40 + sa1 * 8) = b1;
        __syncthreads();
        short8 af[4], bfr[4];
#pragma unroll
        for (int mt = 0; mt < 4; ++mt)
            af[mt] = *(const short8*)(As + (wm * 64 + mt * 16 + m16) * 40 + quad * 8);
#pragma unroll
        for (int nt = 0; nt < 4; ++nt)
            bfr[nt] = *(const short8*)(Bs + (wn * 64 + nt * 16 + m16) * 40 + quad * 8);
#pragma unroll
        for (int mt = 0; mt < 4; ++mt)
#pragma unroll
            for (int nt = 0; nt < 4; ++nt)
                acc[mt][nt] = __builtin_amdgcn_mfma_f32_16x16x32_bf16(
                    af[mt], bfr[nt], acc[mt][nt], 0, 0, 0);
        __syncthreads();
    }
#pragma unroll
    for (int mt = 0; mt < 4; ++mt) {
#pragma unroll
        for (int nt = 0; nt < 4; ++nt) {
            int col = c0 + wn * 64 + nt * 16 + m16;
            if (col >= Cc) continue;
            float bv = bias ? bias[col] : 0.f;
#pragma unroll
            for (int i = 0; i < 4; ++i) {
                int row = r0 + wm * 64 + mt * 16 + quad * 4 + i;
                if (row < R) C[(size_t)row * Cc + col] = acc[mt][nt][i] + bv;
            }
        }
    }
}

// ---------------------------------------------------------------------------
// f32 GEMM (kept for the small lin layer): C = act(A @ B^T + bias)
// ---------------------------------------------------------------------------
__global__ __launch_bounds__(256)
void k_gemm(const float* __restrict__ A, const float* __restrict__ B,
            const float* __restrict__ bias, float* __restrict__ C,
            int R, int Cc, int K, int actTanh)
{
    __shared__ __align__(16) float Asm[16][132];
    __shared__ __align__(16) float Bsm[16][132];
    const int tid = threadIdx.x;
    const int r0 = blockIdx.y * 128, c0 = blockIdx.x * 128;
    const int li = tid >> 1, lk = (tid & 1) * 8;
    const int tx = tid & 15, ty = tid >> 4;
    float acc[8][8];
#pragma unroll
    for (int i = 0; i < 8; ++i)
#pragma unroll
        for (int j = 0; j < 8; ++j) acc[i][j] = 0.f;
    const int nch = (K + 15) >> 4;
    for (int ch = 0; ch < nch; ++ch) {
        const int k0 = ch * 16;
        {
            float v[8];
            int gr = r0 + li, kb = k0 + lk;
            if (gr < R && kb + 8 <= K) {
                const float* p = A + (size_t)gr * K + kb;
                *(float4*)&v[0] = *(const float4*)p;
                *(float4*)&v[4] = *(const float4*)(p + 4);
            } else {
#pragma unroll
                for (int z = 0; z < 8; ++z) {
                    int k = kb + z;
                    v[z] = (gr < R && k < K) ? A[(size_t)gr * K + k] : 0.f;
                }
            }
#pragma unroll
            for (int z = 0; z < 8; ++z) Asm[lk + z][li] = v[z];
        }
        {
            float v[8];
            int gr = c0 + li, kb = k0 + lk;
            if (gr < Cc && kb + 8 <= K) {
                const float* p = B + (size_t)gr * K + kb;
                *(float4*)&v[0] = *(const float4*)p;
                *(float4*)&v[4] = *(const float4*)(p + 4);
            } else {
#pragma unroll
                for (int z = 0; z < 8; ++z) {
                    int k = kb + z;
                    v[z] = (gr < Cc && k < K) ? B[(size_t)gr * K + k] : 0.f;
                }
            }
#pragma unroll
            for (int z = 0; z < 8; ++z) Bsm[lk + z][li] = v[z];
        }
        __syncthreads();
#pragma unroll
        for (int kk = 0; kk < 16; ++kk) {
            float a[8], b[8];
            *(float4*)&a[0] = *(const float4*)&Asm[kk][ty * 8];
            *(float4*)&a[4] = *(const float4*)&Asm[kk][ty * 8 + 4];
            *(float4*)&b[0] = *(const float4*)&Bsm[kk][tx * 8];
            *(float4*)&b[4] = *(const float4*)&Bsm[kk][tx * 8 + 4];
#pragma unroll
            for (int i = 0; i < 8; ++i)
#pragma unroll
                for (int j = 0; j < 8; ++j) acc[i][j] = fmaf(a[i], b[j], acc[i][j]);
        }
        __syncthreads();
    }
#pragma unroll
    for (int i = 0; i < 8; ++i) {
        int r = r0 + ty * 8 + i;
        if (r >= R) continue;
#pragma unroll
        for (int j = 0; j < 8; ++j) {
            int c = c0 + tx * 8 + j;
            if (c >= Cc) continue;
            float v = acc[i][j];
            if (bias) v += bias[c];
            if (actTanh) v = tanhf(v);
            C[(size_t)r * Cc + c] = v;
        }
    }
}

// ---------------------------------------------------------------------------
// Utterance GRU scan, G=1 streaming: block=(n,d), thread a<900 streams bf16
// gate-row a from L2 each step; h broadcast from LDS. ds[a] = dot + bhh[a].
// ---------------------------------------------------------------------------
__global__ __launch_bounds__(960, 1)
void k_utt_scan(const short* __restrict__ Whh,   // [2][900][304] bf16
                const float* __restrict__ bhh,
                const float* __restrict__ gi,    // [L*128][1800] f32
                const int* __restrict__ lens,
                float* __restrict__ maxpool)
{
    const int d = blockIdx.y, n = blockIdx.x, tid = threadIdx.x;
    __shared__ __align__(16) float hs[WS];
    __shared__ float ds[904];
    if (tid < WS) hs[tid] = 0.f;
    const int len = lens[n];
    float b3 = 0.f;
    if (tid < 900) b3 = bhh[d * 900 + tid];
    float m = -1e30f;
    __syncthreads();
    for (int t = 0; t < len; ++t) {            // len is block-uniform
        if (tid < 900) {
            const uint4* wp = (const uint4*)(Whh + ((size_t)d * 900 + tid) * WS);
            const float4* hp = (const float4*)hs;
            float acc = 0.f;
#pragma unroll 8
            for (int c = 0; c < 38; ++c) {
                uint4 wv = wp[c];
                float4 ha = hp[2 * c], hb = hp[2 * c + 1];
                float l0, u0, l1, u1, l2, u2, l3, u3;
                bfp(wv.x, l0, u0); bfp(wv.y, l1, u1);
                bfp(wv.z, l2, u2); bfp(wv.w, l3, u3);
                acc = fmaf(l0, ha.x, acc); acc = fmaf(u0, ha.y, acc);
                acc = fmaf(l1, ha.z, acc); acc = fmaf(u1, ha.w, acc);
                acc = fmaf(l2, hb.x, acc); acc = fmaf(u2, hb.y, acc);
                acc = fmaf(l3, hb.z, acc); acc = fmaf(u3, hb.w, acc);
            }
            ds[tid] = acc + b3;
        }
        __syncthreads();
        if (tid < 300) {
            int ts = d ? (len - 1 - t) : t;
            size_t row = ((size_t)(ts * NN + n)) * 1800 + d * 900 + tid;
            float r = sigm(gi[row] + ds[tid]);
            float z = sigm(gi[row + 300] + ds[tid + 300]);
            float nv = tanhf(gi[row + 600] + r * ds[tid + 600]);
            float hv = (1.f - z) * nv + z * hs[tid];
            hs[tid] = hv;
            m = fmaxf(m, hv);
        }
        __syncthreads();
    }
    if (tid < 300) {
        if (len < LL) m = fmaxf(m, 0.f);       // padded steps contribute 0
        maxpool[(size_t)n * 600 + d * 300 + tid] = m;
    }
}

// ---------------------------------------------------------------------------
__global__ void k_init_query(const float* __restrict__ u, float* __restrict__ query)
{
    int q = blockIdx.x;
    for (int e = threadIdx.x; e < 300; e += blockDim.x)
        query[(size_t)q * 300 + e] = u[(size_t)(q + 1) * 300 + e];
}

// ctx rows -> bf16 [5080][320] padded
__global__ void k_build_ctxA(const float* __restrict__ u, short* __restrict__ Actx)
{
    int rkq = blockIdx.x;            // k*127 + q
    int k = rkq / NQ, q = rkq - k * NQ;
    int src = q + 1 - KWIN + k;
    int e = threadIdx.x;             // 320 threads
    float v = (e < 300 && src >= 0) ? u[(size_t)src * 300 + e] : 0.f;
    Actx[(size_t)rkq * KP + e] = f2bf(v);
}

// ---------------------------------------------------------------------------
// Context GRU scan, G=1 streaming. Writes hout[d][q][slot][300].
// ---------------------------------------------------------------------------
__global__ __launch_bounds__(960, 1)
void k_ctx_scan(const short* __restrict__ Whh,   // [2][900][304] bf16
                const float* __restrict__ bhh,
                const float* __restrict__ gi,    // [40*127][1800] f32
                float* __restrict__ hout)        // [2][127][40][300]
{
    const int d = blockIdx.y, q = blockIdx.x, tid = threadIdx.x;
    __shared__ __align__(16) float hs[WS];
    __shared__ float ds[904];
    if (tid < WS) hs[tid] = 0.f;
    float b3 = 0.f;
    if (tid < 900) b3 = bhh[d * 900 + tid];
    __syncthreads();
    for (int t = 0; t < KEFF; ++t) {
        if (tid < 900) {
            const uint4* wp = (const uint4*)(Whh + ((size_t)d * 900 + tid) * WS);
            const float4* hp = (const float4*)hs;
            float acc = 0.f;
#pragma unroll 8
            for (int c = 0; c < 38; ++c) {
                uint4 wv = wp[c];
                float4 ha = hp[2 * c], hb = hp[2 * c + 1];
                float l0, u0, l1, u1, l2, u2, l3, u3;
                bfp(wv.x, l0, u0); bfp(wv.y, l1, u1);
                bfp(wv.z, l2, u2); bfp(wv.w, l3, u3);
                acc = fmaf(l0, ha.x, acc); acc = fmaf(u0, ha.y, acc);
                acc = fmaf(l1, ha.z, acc); acc = fmaf(u1, ha.w, acc);
                acc = fmaf(l2, hb.x, acc); acc = fmaf(u2, hb.y, acc);
                acc = fmaf(l3, hb.z, acc); acc = fmaf(u3, hb.w, acc);
            }
            ds[tid] = acc + b3;
        }
        __syncthreads();
        if (tid < 300) {
            int ts = d ? (KEFF - 1 - t) : t;
            size_t row = ((size_t)(ts * NQ + q)) * 1800 + d * 900 + tid;
            float r = sigm(gi[row] + ds[tid]);
            float z = sigm(gi[row + 300] + ds[tid + 300]);
            float nv = tanhf(gi[row + 600] + r * ds[tid + 600]);
            float hv = (1.f - z) * nv + z * hs[tid];
            hs[tid] = hv;
            hout[(((size_t)d * NQ + q) * KEFF + ts) * 300 + tid] = hv;
        }
        __syncthreads();
    }
}

// ---------------------------------------------------------------------------
// mem_bank (f32, [q][k][e]) + mrkq (bf16 padded, [k*127+q][320])
// ---------------------------------------------------------------------------
__global__ void k_combine(const float* __restrict__ u, const float* __restrict__ hout,
                          float* __restrict__ mem_bank, short* __restrict__ mrkq)
{
    int rkq = blockIdx.x;            // k*127 + q
    int k = rkq / NQ, q = rkq - k * NQ;
    int src = q + 1 - KWIN + k;
    int e = threadIdx.x;             // 320 threads
    float v = 0.f;
    if (e < 300) {
        float c = (src >= 0) ? u[(size_t)src * 300 + e] : 0.f;
        v = c + hout[((size_t)q * KEFF + k) * 300 + e]
              + hout[(((size_t)NQ + q) * KEFF + k) * 300 + e];
        mem_bank[((size_t)q * KEFF + k) * 300 + e] = v;
    }
    mrkq[(size_t)rkq * KP + e] = f2bf(v);
}

// ---------------------------------------------------------------------------
__global__ __launch_bounds__(64)
void k_score(const float* __restrict__ query, const float* __restrict__ mem_bank,
             float* __restrict__ scores)
{
    const int q = blockIdx.x;
    __shared__ float qv[300];
    for (int e = threadIdx.x; e < 300; e += 64) qv[e] = query[(size_t)q * 300 + e];
    __syncthreads();
    int k = threadIdx.x;
    float s = -1e30f;
    if (k < KEFF) {
        const float* m = mem_bank + ((size_t)q * KEFF + k) * 300;
        float acc = 0.f;
        for (int e = 0; e < 300; ++e) acc = fmaf(qv[e], m[e], acc);
        s = (k < KWIN - 1 - q) ? -1e10f : acc;
    }
    float mx = s;
    for (int o = 32; o > 0; o >>= 1) mx = fmaxf(mx, __shfl_xor(mx, o));
    float e = (k < KEFF) ? __expf(s - mx) : 0.f;
    float sm = e;
    for (int o = 32; o > 0; o >>= 1) sm += __shfl_xor(sm, o);
    if (k < KEFF) scores[q * KEFF + k] = e / sm;
}

// ---------------------------------------------------------------------------
// AttnGRU scan, G=1 streaming: wAtt[hd] has 600 rows (Ur 0..299, Uw 300..599).
// ds[a] includes bias (bur for a<300, bu for a>=300).
// ---------------------------------------------------------------------------
__global__ __launch_bounds__(640, 1)
void k_att_scan(const short* __restrict__ wAtt,   // [6][600][304] bf16
                const float* __restrict__ burb,   // [6*300]
                const float* __restrict__ bub,    // [6*300]
                const float* __restrict__ xgr,    // [5080][1800] f32
                const float* __restrict__ xgw,
                const float* __restrict__ scores, // [127][40]
                float* __restrict__ hbuf,         // [2][127][300]
                int hop)
{
    const int d = blockIdx.y, q = blockIdx.x, tid = threadIdx.x;
    const int hd = hop * 2 + d;
    __shared__ __align__(16) float hs[WS];
    __shared__ float ds[600];
    if (tid < WS) hs[tid] = 0.f;
    float bb = 0.f;
    if (tid < 300) bb = burb[hd * 300 + tid];
    else if (tid < 600) bb = bub[hd * 300 + (tid - 300)];
    __syncthreads();
    for (int t = 0; t < KEFF; ++t) {
        if (tid < 600) {
            const uint4* wp = (const uint4*)(wAtt + ((size_t)hd * 600 + tid) * WS);
            const float4* hp = (const float4*)hs;
            float acc = 0.f;
#pragma unroll 8
            for (int c = 0; c < 38; ++c) {
                uint4 wv = wp[c];
                float4 ha = hp[2 * c], hb = hp[2 * c + 1];
                float l0, u0, l1, u1, l2, u2, l3, u3;
                bfp(wv.x, l0, u0); bfp(wv.y, l1, u1);
                bfp(wv.z, l2, u2); bfp(wv.w, l3, u3);
                acc = fmaf(l0, ha.x, acc); acc = fmaf(u0, ha.y, acc);
                acc = fmaf(l1, ha.z, acc); acc = fmaf(u1, ha.w, acc);
                acc = fmaf(l2, hb.x, acc); acc = fmaf(u2, hb.y, acc);
                acc = fmaf(l3, hb.z, acc); acc = fmaf(u3, hb.w, acc);
            }
            ds[tid] = acc + bb;
        }
        __syncthreads();
        if (tid < 300) {
            int kq = d ? (KEFF - 1 - t) : t;
            float gt = scores[q * KEFF + kq];
            size_t xi = ((size_t)(kq * NQ + q)) * 1800 + (size_t)hd * 300 + tid;
            float r = sigm(xgr[xi] + ds[tid]);
            float ht = tanhf(xgw[xi] + r * ds[tid + 300]);
            hs[tid] = gt * ht + (1.f - gt) * hs[tid];
        }
        __syncthreads();
    }
    if (tid < 300)
        hbuf[((size_t)d * NQ + q) * 300 + tid] = hs[tid];
}

__global__ void k_qupd(float* __restrict__ query, const float* __restrict__ hbuf)
{
    int q = blockIdx.x;
    for (int e = threadIdx.x; e < 300; e += blockDim.x)
        query[(size_t)q * 300 + e] += hbuf[(size_t)q * 300 + e]
                                    + hbuf[(size_t)(NQ + q) * 300 + e];
}

// ---------------------------------------------------------------------------
__global__ __launch_bounds__(64)
void k_cls(const float* __restrict__ u, const float* __restrict__ query,
           const float* __restrict__ cw, const float* __restrict__ cb,
           float* __restrict__ out)
{
    int n = blockIdx.x;
    const float* srow = (n == 0) ? u : (query + (size_t)(n - 1) * 300);
    int c = threadIdx.x & 7;
    int part = threadIdx.x >> 3;
    float p = 0.f;
    if (c < NCLS) {
        for (int e = part; e < 300; e += 8) p = fmaf(srow[e], cw[c * 300 + e], p);
    }
    p += __shfl_xor(p, 8);
    p += __shfl_xor(p, 16);
    p += __shfl_xor(p, 32);
    if (part == 0 && c < NCLS) out[n * NCLS + c] = p + cb[c];
}

// ---------------------------------------------------------------------------
extern "C" void kernel_launch(void* const* d_in, const int* in_sizes, int n_in,
                              void* d_out, int out_size, void* d_ws, size_t ws_size,
                              hipStream_t stream)
{
    const int* ids  = (const int*)d_in[0];
    const int* lens = (const int*)d_in[1];
    const float* emb   = (const float*)d_in[2];
    const float* uWih  = (const float*)d_in[3];
    const float* uWhh  = (const float*)d_in[4];
    const float* ubih  = (const float*)d_in[5];
    const float* ubhh  = (const float*)d_in[6];
    const float* linw  = (const float*)d_in[7];
    const float* linb  = (const float*)d_in[8];
    const float* cWih  = (const float*)d_in[9];
    const float* cWhh  = (const float*)d_in[10];
    const float* cbih  = (const float*)d_in[11];
    const float* cbhh  = (const float*)d_in[12];
    const float* aWr_w = (const float*)d_in[13];
    const float* aWr_b = (const float*)d_in[14];
    const float* aUr_w = (const float*)d_in[15];
    const float* aUr_b = (const float*)d_in[16];
    const float* aW_w  = (const float*)d_in[17];
    const float* aW_b  = (const float*)d_in[18];
    const float* aU_w  = (const float*)d_in[19];
    const float* aU_b  = (const float*)d_in[20];
    const float* clsw  = (const float*)d_in[21];
    const float* clsb  = (const float*)d_in[22];
    float* out = (float*)d_out;
    (void)in_sizes; (void)n_in; (void)out_size; (void)ws_size;

    char* base = (char*)d_ws;
    size_t off = 0;
    auto alloc = [&](size_t b) -> void* {
        void* r = (void*)(base + off);
        off += (b + 255) & ~(size_t)255;
        return r;
    };
    short* A_utt  = (short*)alloc((size_t)8192 * KP * 2);          //  5.2 MB
    float* giU    = (float*)alloc((size_t)8192 * 1800 * 4);        // 59.0 MB (reused: xgr)
    float* giC    = (float*)alloc((size_t)5080 * 1800 * 4);        // 36.6 MB (reused: xgw)
    short* wUihB  = (short*)alloc((size_t)1800 * KP * 2);
    short* wCihB  = (short*)alloc((size_t)1800 * KP * 2);
    short* wArB   = (short*)alloc((size_t)1800 * KP * 2);
    short* wAwB   = (short*)alloc((size_t)1800 * KP * 2);
    short* wUhhB  = (short*)alloc((size_t)1800 * WS * 2);
    short* wChhB  = (short*)alloc((size_t)1800 * WS * 2);
    short* wAttB  = (short*)alloc((size_t)3600 * WS * 2);
    short* Actx   = (short*)alloc((size_t)5080 * KP * 2);
    float* hout   = (float*)alloc((size_t)2 * NQ * KEFF * 300 * 4);
    float* membank= (float*)alloc((size_t)NQ * KEFF * 300 * 4);
    short* mrkq   = (short*)alloc((size_t)5080 * KP * 2);
    float* mpool  = (float*)alloc((size_t)NN * 600 * 4);
    float* uu     = (float*)alloc((size_t)NN * 300 * 4);
    float* query  = (float*)alloc((size_t)NQ * 300 * 4);
    float* scores = (float*)alloc((size_t)NQ * KEFF * 4);
    float* hbuf   = (float*)alloc((size_t)2 * NQ * 300 * 4);
    float* xgr = giU;   // giU dead after k_utt_scan
    float* xgw = giC;   // giC dead after k_ctx_scan

    const int RKQ = NQ * KEFF;  // 5080

    // 0) conversions (weights -> bf16, padded)
    k_conv320<<<dim3(1800), dim3(320), 0, stream>>>(uWih, wUihB);
    k_conv320<<<dim3(1800), dim3(320), 0, stream>>>(cWih, wCihB);
    k_conv320<<<dim3(1800), dim3(320), 0, stream>>>(aWr_w, wArB);
    k_conv320<<<dim3(1800), dim3(320), 0, stream>>>(aW_w, wAwB);
    k_conv304<<<dim3(1800), dim3(304), 0, stream>>>(uWhh, wUhhB);
    k_conv304<<<dim3(1800), dim3(304), 0, stream>>>(cWhh, wChhB);
    k_conv_att<<<dim3(3600), dim3(304), 0, stream>>>(aUr_w, aU_w, wAttB);

    // 1) gather, 2) utt input-gate GEMM (MFMA), 3) utt scan + maxpool
    k_gather_bf16<<<dim3(LL * NN), dim3(320), 0, stream>>>(emb, ids, A_utt);
    k_mgemm<<<dim3(15, 64), dim3(256), 0, stream>>>(A_utt, wUihB, ubih, giU, 8192, 1800);
    k_utt_scan<<<dim3(NN, 2), dim3(960), 0, stream>>>(wUhhB, ubhh, giU, lens, mpool);
    // 4) u = tanh(maxpool @ lin_w.T + lin_b)  (small f32 GEMM)
    k_gemm<<<dim3(3, 1), dim3(256), 0, stream>>>(mpool, linw, linb, uu, NN, 300, 600, 1);
    // 5) query init + ctx rows
    k_init_query<<<dim3(NQ), dim3(128), 0, stream>>>(uu, query);
    k_build_ctxA<<<dim3(RKQ), dim3(320), 0, stream>>>(uu, Actx);
    // 6) ctx input-gate GEMM + ctx scan + combine
    k_mgemm<<<dim3(15, 40), dim3(256), 0, stream>>>(Actx, wCihB, cbih, giC, RKQ, 1800);
    k_ctx_scan<<<dim3(NQ, 2), dim3(960), 0, stream>>>(wChhB, cbhh, giC, hout);
    k_combine<<<dim3(RKQ), dim3(320), 0, stream>>>(uu, hout, membank, mrkq);
    // 7) attention x-projections (all hops/dirs)
    k_mgemm<<<dim3(15, 40), dim3(256), 0, stream>>>(mrkq, wArB, aWr_b, xgr, RKQ, 1800);
    k_mgemm<<<dim3(15, 40), dim3(256), 0, stream>>>(mrkq, wAwB, aW_b, xgw, RKQ, 1800);
    // 8) hops
    for (int hop = 0; hop < 3; ++hop) {
        k_score<<<dim3(NQ), dim3(64), 0, stream>>>(query, membank, scores);
        k_att_scan<<<dim3(NQ, 2), dim3(640), 0, stream>>>(wAttB, aUr_b, aU_b,
                                                          xgr, xgw, scores, hbuf, hop);
        k_qupd<<<dim3(NQ), dim3(128), 0, stream>>>(query, hbuf);
    }
    // 9) classifier
    k_cls<<<dim3(NN), dim3(64), 0, stream>>>(uu, query, clsw, clsb, out);
}

// Round 5
// 1473.081 us; speedup vs baseline: 7.7121x; 1.8389x over previous
//
#include <hip/hip_runtime.h>

// ---- static config ----
static constexpr int NN   = 128;   // dialogues
static constexpr int LL   = 64;    // utterance length
static constexpr int KWIN = 40;
static constexpr int KEFF = 40;
static constexpr int NQ   = 127;   // N-1
static constexpr int NCLS = 6;
static constexpr int KP   = 320;   // padded K for MFMA GEMMs (300 -> 320)

typedef __attribute__((ext_vector_type(8))) short short8;
typedef __attribute__((ext_vector_type(4))) float floatx4;

__device__ __forceinline__ float sigm(float x) { return 1.f / (1.f + __expf(-x)); }
__device__ __forceinline__ short f2bf(float f) {
    unsigned x = __float_as_uint(f);
    unsigned r = (x + 0x7fffu + ((x >> 16) & 1u)) >> 16;
    return (short)r;
}
__device__ __forceinline__ void bfp(unsigned v, float& lo, float& hi) {
    lo = __uint_as_float(v << 16);
    hi = __uint_as_float(v & 0xffff0000u);
}
__device__ __forceinline__ void dot8(uint4 wv, float4 h0, float4 h1, float& acc) {
    float l0, u0, l1, u1, l2, u2, l3, u3;
    bfp(wv.x, l0, u0); bfp(wv.y, l1, u1);
    bfp(wv.z, l2, u2); bfp(wv.w, l3, u3);
    acc = fmaf(l0, h0.x, acc); acc = fmaf(u0, h0.y, acc);
    acc = fmaf(l1, h0.z, acc); acc = fmaf(u1, h0.w, acc);
    acc = fmaf(l2, h1.x, acc); acc = fmaf(u2, h1.y, acc);
    acc = fmaf(l3, h1.z, acc); acc = fmaf(u3, h1.w, acc);
}

// ---------------------------------------------------------------------------
// Gather + convert: A[r=t*128+n][0..319] = bf16(emb[ids[n*64+t]]), zero-pad
// ---------------------------------------------------------------------------
__global__ void k_gather_bf16(const float* __restrict__ emb,
                              const int* __restrict__ ids,
                              short* __restrict__ A)
{
    int r = blockIdx.x;            // t*128 + n
    int n = r & (NN - 1);
    int t = r >> 7;
    int id = ids[n * LL + t];
    int e = threadIdx.x;           // 320 threads
    float v = (e < 300) ? emb[(size_t)id * 300 + e] : 0.f;
    A[(size_t)r * KP + e] = f2bf(v);
}

// f32 [rows][300] -> bf16 [rows][320], zero pad (GEMM operands)
__global__ void k_conv320(const float* __restrict__ src, short* __restrict__ dst)
{
    int r = blockIdx.x, e = threadIdx.x;   // 320 threads
    float v = (e < 300) ? src[(size_t)r * 300 + e] : 0.f;
    dst[(size_t)r * KP + e] = f2bf(v);
}

// ---------------------------------------------------------------------------
// Pack GRU Whh [2][900][300] f32 -> chunk-interleaved bf16 [2][39][912][8sh]
// thread u=(p*300+m) owns rows {m, m+300, m+600} cols [100p,100p+100)
// chunk c = cs*3+s : 8 bf16 of row (s*300+m), cols 100p+8cs .. +8 (0 if >=100)
// ---------------------------------------------------------------------------
__global__ void k_pack_gru(const float* __restrict__ W, short* __restrict__ dst)
{
    int idx = blockIdx.x * 256 + threadIdx.x;
    if (idx >= 2 * 39 * 900) return;
    int u = idx % 900, dc = idx / 900;
    int c = dc % 39, d = dc / 39;
    int cs = c / 3, s = c - cs * 3;
    int p = u / 300, m = u - p * 300;
    const float* src = W + ((size_t)d * 900 + s * 300 + m) * 300 + p * 100;
    short v[8];
#pragma unroll
    for (int i = 0; i < 8; ++i) {
        int cl = cs * 8 + i;
        v[i] = (cl < 100) ? f2bf(src[cl]) : (short)0;
    }
    short8 sv;
#pragma unroll
    for (int i = 0; i < 8; ++i) sv[i] = v[i];
    *(short8*)(dst + ((size_t)(d * 39 + c) * 912 + u) * 8) = sv;
}

// ---------------------------------------------------------------------------
// Pack attn Ur/Uw [6][300][300] -> [6][40][608][8sh]
// thread u=(p*300+m): p=0 cols [0,160), p=1 cols [160,300); rows Ur_m / Uw_m
// chunk c = cs*2+s (s=0:Ur, 1:Uw), cols 160p+8cs .. +8 (0 beyond limit)
// ---------------------------------------------------------------------------
__global__ void k_pack_att(const float* __restrict__ Ur, const float* __restrict__ Uw,
                           short* __restrict__ dst)
{
    int idx = blockIdx.x * 256 + threadIdx.x;
    if (idx >= 6 * 40 * 600) return;
    int u = idx % 600, hc = idx / 600;
    int c = hc % 40, hd = hc / 40;
    int cs = c >> 1, s = c & 1;
    int p = u / 300, m = u - p * 300;
    int lim = p ? 140 : 160;
    const float* src = (s ? Uw : Ur) + ((size_t)hd * 300 + m) * 300 + 160 * p;
    short v[8];
#pragma unroll
    for (int i = 0; i < 8; ++i) {
        int cl = cs * 8 + i;
        v[i] = (cl < lim) ? f2bf(src[cl]) : (short)0;
    }
    short8 sv;
#pragma unroll
    for (int i = 0; i < 8; ++i) sv[i] = v[i];
    *(short8*)(dst + ((size_t)(hd * 40 + c) * 608 + u) * 8) = sv;
}

// ---------------------------------------------------------------------------
// bf16 MFMA GEMM (B^T layout): C[r,c] = sum_k A[r,k]*B[c,k] + bias[c], f32 out
// ---------------------------------------------------------------------------
__global__ __launch_bounds__(256)
void k_mgemm(const short* __restrict__ A, const short* __restrict__ B,
             const float* __restrict__ bias, float* __restrict__ C,
             int R, int Cc)
{
    __shared__ short As[128 * 40];
    __shared__ short Bs[128 * 40];
    const int tid = threadIdx.x;
    const int r0 = blockIdx.y * 128, c0 = blockIdx.x * 128;
    const int w = tid >> 6, lane = tid & 63;
    const int m16 = lane & 15, quad = lane >> 4;
    const int wm = w & 1, wn = w >> 1;
    floatx4 acc[4][4];
#pragma unroll
    for (int i = 0; i < 4; ++i)
#pragma unroll
        for (int j = 0; j < 4; ++j) acc[i][j] = (floatx4){0.f, 0.f, 0.f, 0.f};

    const int ra0 = tid >> 2,         sa0 = tid & 3;
    const int ra1 = (tid + 256) >> 2, sa1 = tid & 3;

    for (int k0 = 0; k0 < KP; k0 += 32) {
        short8 za = {0,0,0,0,0,0,0,0};
        short8 a0 = za, a1 = za, b0 = za, b1 = za;
        if (r0 + ra0 < R) a0 = *(const short8*)(A + (size_t)(r0 + ra0) * KP + k0 + sa0 * 8);
        if (r0 + ra1 < R) a1 = *(const short8*)(A + (size_t)(r0 + ra1) * KP + k0 + sa1 * 8);
        if (c0 + ra0 < Cc) b0 = *(const short8*)(B + (size_t)(c0 + ra0) * KP + k0 + sa0 * 8);
        if (c0 + ra1 < Cc) b1 = *(const short8*)(B + (size_t)(c0 + ra1) * KP + k0 + sa1 * 8);
        *(short8*)(As + ra0 * 40 + sa0 * 8) = a0;
        *(short8*)(As + ra1 * 40 + sa1 * 8) = a1;
        *(short8*)(Bs + ra0 * 40 + sa0 * 8) = b0;
        *(short8*)(Bs + ra1 * 40 + sa1 * 8) = b1;
        __syncthreads();
        short8 af[4], bfr[4];
#pragma unroll
        for (int mt = 0; mt < 4; ++mt)
            af[mt] = *(const short8*)(As + (wm * 64 + mt * 16 + m16) * 40 + quad * 8);
#pragma unroll
        for (int nt = 0; nt < 4; ++nt)
            bfr[nt] = *(const short8*)(Bs + (wn * 64 + nt * 16 + m16) * 40 + quad * 8);
#pragma unroll
        for (int mt = 0; mt < 4; ++mt)
#pragma unroll
            for (int nt = 0; nt < 4; ++nt)
                acc[mt][nt] = __builtin_amdgcn_mfma_f32_16x16x32_bf16(
                    af[mt], bfr[nt], acc[mt][nt], 0, 0, 0);
        __syncthreads();
    }
#pragma unroll
    for (int mt = 0; mt < 4; ++mt) {
#pragma unroll
        for (int nt = 0; nt < 4; ++nt) {
            int col = c0 + wn * 64 + nt * 16 + m16;
            if (col >= Cc) continue;
            float bv = bias ? bias[col] : 0.f;
#pragma unroll
            for (int i = 0; i < 4; ++i) {
                int row = r0 + wm * 64 + mt * 16 + quad * 4 + i;
                if (row < R) C[(size_t)row * Cc + col] = acc[mt][nt][i] + bv;
            }
        }
    }
}

// ---------------------------------------------------------------------------
// f32 GEMM (small lin layer): C = act(A @ B^T + bias)
// ---------------------------------------------------------------------------
__global__ __launch_bounds__(256)
void k_gemm(const float* __restrict__ A, const float* __restrict__ B,
            const float* __restrict__ bias, float* __restrict__ C,
            int R, int Cc, int K, int actTanh)
{
    __shared__ __align__(16) float Asm[16][132];
    __shared__ __align__(16) float Bsm[16][132];
    const int tid = threadIdx.x;
    const int r0 = blockIdx.y * 128, c0 = blockIdx.x * 128;
    const int li = tid >> 1, lk = (tid & 1) * 8;
    const int tx = tid & 15, ty = tid >> 4;
    float acc[8][8];
#pragma unroll
    for (int i = 0; i < 8; ++i)
#pragma unroll
        for (int j = 0; j < 8; ++j) acc[i][j] = 0.f;
    const int nch = (K + 15) >> 4;
    for (int ch = 0; ch < nch; ++ch) {
        const int k0 = ch * 16;
        {
            float v[8];
            int gr = r0 + li, kb = k0 + lk;
            if (gr < R && kb + 8 <= K) {
                const float* p = A + (size_t)gr * K + kb;
                *(float4*)&v[0] = *(const float4*)p;
                *(float4*)&v[4] = *(const float4*)(p + 4);
            } else {
#pragma unroll
                for (int z = 0; z < 8; ++z) {
                    int k = kb + z;
                    v[z] = (gr < R && k < K) ? A[(size_t)gr * K + k] : 0.f;
                }
            }
#pragma unroll
            for (int z = 0; z < 8; ++z) Asm[lk + z][li] = v[z];
        }
        {
            float v[8];
            int gr = c0 + li, kb = k0 + lk;
            if (gr < Cc && kb + 8 <= K) {
                const float* p = B + (size_t)gr * K + kb;
                *(float4*)&v[0] = *(const float4*)p;
                *(float4*)&v[4] = *(const float4*)(p + 4);
            } else {
#pragma unroll
                for (int z = 0; z < 8; ++z) {
                    int k = kb + z;
                    v[z] = (gr < Cc && k < K) ? B[(size_t)gr * K + k] : 0.f;
                }
            }
#pragma unroll
            for (int z = 0; z < 8; ++z) Bsm[lk + z][li] = v[z];
        }
        __syncthreads();
#pragma unroll
        for (int kk = 0; kk < 16; ++kk) {
            float a[8], b[8];
            *(float4*)&a[0] = *(const float4*)&Asm[kk][ty * 8];
            *(float4*)&a[4] = *(const float4*)&Asm[kk][ty * 8 + 4];
            *(float4*)&b[0] = *(const float4*)&Bsm[kk][tx * 8];
            *(float4*)&b[4] = *(const float4*)&Bsm[kk][tx * 8 + 4];
#pragma unroll
            for (int i = 0; i < 8; ++i)
#pragma unroll
                for (int j = 0; j < 8; ++j) acc[i][j] = fmaf(a[i], b[j], acc[i][j]);
        }
        __syncthreads();
    }
#pragma unroll
    for (int i = 0; i < 8; ++i) {
        int r = r0 + ty * 8 + i;
        if (r >= R) continue;
#pragma unroll
        for (int j = 0; j < 8; ++j) {
            int c = c0 + tx * 8 + j;
            if (c >= Cc) continue;
            float v = acc[i][j];
            if (bias) v += bias[c];
            if (actTanh) v = tanhf(v);
            C[(size_t)r * Cc + c] = v;
        }
    }
}

// ---------------------------------------------------------------------------
// GRU scan core (utt & ctx): thread u=(p,m) owns 3 gate-rows over cols
// [100p,100p+100); h chunk read once, reused for 3 rows; weight chunks
// interleaved+coalesced, double-buffered. IS_UTT: gated by len + maxpool.
// ---------------------------------------------------------------------------
template<bool IS_UTT>
__device__ __forceinline__ void gru_scan_body(
    const short* __restrict__ Wp,   // [2][39][912][8sh]
    const float* __restrict__ bhh,
    const float* __restrict__ gi,   // [T*NB][1800]
    int d, int chain, int NB, int len,
    float* __restrict__ outp)       // maxpool row (utt) or hout base (ctx)
{
    const int tid = threadIdx.x;
    __shared__ __align__(16) float hs[304];
    __shared__ float pds[3][3][304];
    if (tid < 304) hs[tid] = 0.f;
    const int p = tid / 300, m = tid - p * 300;  // valid for tid<900
    float br = 0.f, bz = 0.f, bn = 0.f;
    if (tid < 300) {
        br = bhh[d * 900 + tid];
        bz = bhh[d * 900 + 300 + tid];
        bn = bhh[d * 900 + 600 + tid];
    }
    const uint4* wb = (const uint4*)(Wp + (size_t)d * 39 * 912 * 8);
    float mx = -1e30f;
    __syncthreads();
    for (int t = 0; t < len; ++t) {
        int ts = d ? (len - 1 - t) : t;
        float g0 = 0.f, g1 = 0.f, g2 = 0.f;
        if (tid < 300) {   // prefetch gate inputs; used after the barrier
            size_t row = ((size_t)(ts * NB + chain)) * 1800 + d * 900 + tid;
            g0 = gi[row]; g1 = gi[row + 300]; g2 = gi[row + 600];
        }
        if (tid < 900) {
            const float4* h4 = (const float4*)hs + p * 25;
            float a0 = 0.f, a1 = 0.f, a2 = 0.f;
            uint4 cur0 = wb[0 * 912 + tid];
            uint4 cur1 = wb[1 * 912 + tid];
            uint4 cur2 = wb[2 * 912 + tid];
#pragma unroll
            for (int cs = 0; cs < 13; ++cs) {
                uint4 n0, n1, n2;
                if (cs < 12) {
                    n0 = wb[((cs + 1) * 3 + 0) * 912 + tid];
                    n1 = wb[((cs + 1) * 3 + 1) * 912 + tid];
                    n2 = wb[((cs + 1) * 3 + 2) * 912 + tid];
                }
                float4 h0 = h4[2 * cs], h1 = h4[2 * cs + 1];
                dot8(cur0, h0, h1, a0);
                dot8(cur1, h0, h1, a1);
                dot8(cur2, h0, h1, a2);
                if (cs < 12) { cur0 = n0; cur1 = n1; cur2 = n2; }
            }
            pds[0][p][m] = a0;
            pds[1][p][m] = a1;
            pds[2][p][m] = a2;
        }
        __syncthreads();
        if (tid < 300) {
            float dr = pds[0][0][tid] + pds[0][1][tid] + pds[0][2][tid] + br;
            float dz = pds[1][0][tid] + pds[1][1][tid] + pds[1][2][tid] + bz;
            float dn = pds[2][0][tid] + pds[2][1][tid] + pds[2][2][tid] + bn;
            float r = sigm(g0 + dr);
            float z = sigm(g1 + dz);
            float nv = tanhf(g2 + r * dn);
            float hv = (1.f - z) * nv + z * hs[tid];
            hs[tid] = hv;
            if (IS_UTT) mx = fmaxf(mx, hv);
            else outp[(size_t)ts * 300 + tid] = hv;
        }
        __syncthreads();
    }
    if (IS_UTT && tid < 300) {
        if (len < LL) mx = fmaxf(mx, 0.f);   // padded steps contribute 0
        outp[tid] = mx;
    }
}

__global__ __launch_bounds__(960, 1)
void k_utt_scan(const short* __restrict__ Wp, const float* __restrict__ bhh,
                const float* __restrict__ gi, const int* __restrict__ lens,
                float* __restrict__ maxpool)
{
    const int d = blockIdx.y, n = blockIdx.x;
    gru_scan_body<true>(Wp, bhh, gi, d, n, NN, lens[n],
                        maxpool + (size_t)n * 600 + d * 300);
}

__global__ __launch_bounds__(960, 1)
void k_ctx_scan(const short* __restrict__ Wp, const float* __restrict__ bhh,
                const float* __restrict__ gi, float* __restrict__ hout)
{
    const int d = blockIdx.y, q = blockIdx.x;
    gru_scan_body<false>(Wp, bhh, gi, d, q, NQ, KEFF,
                         hout + (((size_t)d * NQ + q) * KEFF) * 300);
}

// ---------------------------------------------------------------------------
__global__ void k_init_query(const float* __restrict__ u, float* __restrict__ query)
{
    int q = blockIdx.x;
    for (int e = threadIdx.x; e < 300; e += blockDim.x)
        query[(size_t)q * 300 + e] = u[(size_t)(q + 1) * 300 + e];
}

// ctx rows -> bf16 [5080][320] padded
__global__ void k_build_ctxA(const float* __restrict__ u, short* __restrict__ Actx)
{
    int rkq = blockIdx.x;            // k*127 + q
    int k = rkq / NQ, q = rkq - k * NQ;
    int src = q + 1 - KWIN + k;
    int e = threadIdx.x;             // 320 threads
    float v = (e < 300 && src >= 0) ? u[(size_t)src * 300 + e] : 0.f;
    Actx[(size_t)rkq * KP + e] = f2bf(v);
}

// ---------------------------------------------------------------------------
__global__ void k_combine(const float* __restrict__ u, const float* __restrict__ hout,
                          float* __restrict__ mem_bank, short* __restrict__ mrkq)
{
    int rkq = blockIdx.x;            // k*127 + q
    int k = rkq / NQ, q = rkq - k * NQ;
    int src = q + 1 - KWIN + k;
    int e = threadIdx.x;             // 320 threads
    float v = 0.f;
    if (e < 300) {
        float c = (src >= 0) ? u[(size_t)src * 300 + e] : 0.f;
        v = c + hout[((size_t)q * KEFF + k) * 300 + e]
              + hout[(((size_t)NQ + q) * KEFF + k) * 300 + e];
        mem_bank[((size_t)q * KEFF + k) * 300 + e] = v;
    }
    mrkq[(size_t)rkq * KP + e] = f2bf(v);
}

// ---------------------------------------------------------------------------
__global__ __launch_bounds__(64)
void k_score(const float* __restrict__ query, const float* __restrict__ mem_bank,
             float* __restrict__ scores)
{
    const int q = blockIdx.x;
    __shared__ float qv[300];
    for (int e = threadIdx.x; e < 300; e += 64) qv[e] = query[(size_t)q * 300 + e];
    __syncthreads();
    int k = threadIdx.x;
    float s = -1e30f;
    if (k < KEFF) {
        const float* m = mem_bank + ((size_t)q * KEFF + k) * 300;
        float acc = 0.f;
        for (int e = 0; e < 300; ++e) acc = fmaf(qv[e], m[e], acc);
        s = (k < KWIN - 1 - q) ? -1e10f : acc;
    }
    float mx = s;
    for (int o = 32; o > 0; o >>= 1) mx = fmaxf(mx, __shfl_xor(mx, o));
    float e = (k < KEFF) ? __expf(s - mx) : 0.f;
    float sm = e;
    for (int o = 32; o > 0; o >>= 1) sm += __shfl_xor(sm, o);
    if (k < KEFF) scores[q * KEFF + k] = e / sm;
}

// ---------------------------------------------------------------------------
// AttnGRU scan: thread u=(p,m) owns rows {Ur_m, Uw_m} over cols
// [160p, 160p+{160,140}); packed chunks [6][40][608]; double-buffered.
// ---------------------------------------------------------------------------
__global__ __launch_bounds__(640, 1)
void k_att_scan(const short* __restrict__ Wp,     // packed
                const float* __restrict__ burb,   // [6*300]
                const float* __restrict__ bub,    // [6*300]
                const float* __restrict__ xgr,    // [5080][1800] f32
                const float* __restrict__ xgw,
                const float* __restrict__ scores, // [127][40]
                float* __restrict__ hbuf,         // [2][127][300]
                int hop)
{
    const int d = blockIdx.y, q = blockIdx.x, tid = threadIdx.x;
    const int hd = hop * 2 + d;
    __shared__ __align__(16) float hs[320];
    __shared__ float pds[2][2][304];
    if (tid < 320) hs[tid] = 0.f;
    const int p = tid / 300, m = tid - p * 300;   // valid tid<600
    float bur = 0.f, bu = 0.f;
    if (tid < 300) { bur = burb[hd * 300 + tid]; bu = bub[hd * 300 + tid]; }
    const uint4* wb = (const uint4*)(Wp + (size_t)hd * 40 * 608 * 8);
    __syncthreads();
    for (int t = 0; t < KEFF; ++t) {
        int kq = d ? (KEFF - 1 - t) : t;
        float xr = 0.f, xw = 0.f, gt = 0.f;
        if (tid < 300) {   // prefetch; used after the barrier
            size_t xi = ((size_t)(kq * NQ + q)) * 1800 + (size_t)hd * 300 + tid;
            xr = xgr[xi]; xw = xgw[xi];
            gt = scores[q * KEFF + kq];
        }
        if (tid < 600) {
            const float4* h4 = (const float4*)hs + p * 40;
            float a0 = 0.f, a1 = 0.f;
            uint4 cur0 = wb[0 * 608 + tid];
            uint4 cur1 = wb[1 * 608 + tid];
#pragma unroll
            for (int cs = 0; cs < 20; ++cs) {
                uint4 n0, n1;
                if (cs < 19) {
                    n0 = wb[((cs + 1) * 2 + 0) * 608 + tid];
                    n1 = wb[((cs + 1) * 2 + 1) * 608 + tid];
                }
                float4 h0 = h4[2 * cs], h1 = h4[2 * cs + 1];
                dot8(cur0, h0, h1, a0);
                dot8(cur1, h0, h1, a1);
                if (cs < 19) { cur0 = n0; cur1 = n1; }
            }
            pds[0][p][m] = a0;
            pds[1][p][m] = a1;
        }
        __syncthreads();
        if (tid < 300) {
            float dr = pds[0][0][tid] + pds[0][1][tid] + bur;
            float dw = pds[1][0][tid] + pds[1][1][tid] + bu;
            float r = sigm(xr + dr);
            float ht = tanhf(xw + r * dw);
            hs[tid] = gt * ht + (1.f - gt) * hs[tid];
        }
        __syncthreads();
    }
    if (tid < 300)
        hbuf[((size_t)d * NQ + q) * 300 + tid] = hs[tid];
}

__global__ void k_qupd(float* __restrict__ query, const float* __restrict__ hbuf)
{
    int q = blockIdx.x;
    for (int e = threadIdx.x; e < 300; e += blockDim.x)
        query[(size_t)q * 300 + e] += hbuf[(size_t)q * 300 + e]
                                    + hbuf[(size_t)(NQ + q) * 300 + e];
}

// ---------------------------------------------------------------------------
__global__ __launch_bounds__(64)
void k_cls(const float* __restrict__ u, const float* __restrict__ query,
           const float* __restrict__ cw, const float* __restrict__ cb,
           float* __restrict__ out)
{
    int n = blockIdx.x;
    const float* srow = (n == 0) ? u : (query + (size_t)(n - 1) * 300);
    int c = threadIdx.x & 7;
    int part = threadIdx.x >> 3;
    float p = 0.f;
    if (c < NCLS) {
        for (int e = part; e < 300; e += 8) p = fmaf(srow[e], cw[c * 300 + e], p);
    }
    p += __shfl_xor(p, 8);
    p += __shfl_xor(p, 16);
    p += __shfl_xor(p, 32);
    if (part == 0 && c < NCLS) out[n * NCLS + c] = p + cb[c];
}

// ---------------------------------------------------------------------------
extern "C" void kernel_launch(void* const* d_in, const int* in_sizes, int n_in,
                              void* d_out, int out_size, void* d_ws, size_t ws_size,
                              hipStream_t stream)
{
    const int* ids  = (const int*)d_in[0];
    const int* lens = (const int*)d_in[1];
    const float* emb   = (const float*)d_in[2];
    const float* uWih  = (const float*)d_in[3];
    const float* uWhh  = (const float*)d_in[4];
    const float* ubih  = (const float*)d_in[5];
    const float* ubhh  = (const float*)d_in[6];
    const float* linw  = (const float*)d_in[7];
    const float* linb  = (const float*)d_in[8];
    const float* cWih  = (const float*)d_in[9];
    const float* cWhh  = (const float*)d_in[10];
    const float* cbih  = (const float*)d_in[11];
    const float* cbhh  = (const float*)d_in[12];
    const float* aWr_w = (const float*)d_in[13];
    const float* aWr_b = (const float*)d_in[14];
    const float* aUr_w = (const float*)d_in[15];
    const float* aUr_b = (const float*)d_in[16];
    const float* aW_w  = (const float*)d_in[17];
    const float* aW_b  = (const float*)d_in[18];
    const float* aU_w  = (const float*)d_in[19];
    const float* aU_b  = (const float*)d_in[20];
    const float* clsw  = (const float*)d_in[21];
    const float* clsb  = (const float*)d_in[22];
    float* out = (float*)d_out;
    (void)in_sizes; (void)n_in; (void)out_size; (void)ws_size;

    char* base = (char*)d_ws;
    size_t off = 0;
    auto alloc = [&](size_t b) -> void* {
        void* r = (void*)(base + off);
        off += (b + 255) & ~(size_t)255;
        return r;
    };
    short* A_utt  = (short*)alloc((size_t)8192 * KP * 2);          //  5.2 MB
    float* giU    = (float*)alloc((size_t)8192 * 1800 * 4);        // 59.0 MB (reused: xgr)
    float* giC    = (float*)alloc((size_t)5080 * 1800 * 4);        // 36.6 MB (reused: xgw)
    short* wUihB  = (short*)alloc((size_t)1800 * KP * 2);
    short* wCihB  = (short*)alloc((size_t)1800 * KP * 2);
    short* wArB   = (short*)alloc((size_t)1800 * KP * 2);
    short* wAwB   = (short*)alloc((size_t)1800 * KP * 2);
    short* wPackU = (short*)alloc((size_t)2 * 39 * 912 * 8 * 2);   // 1.14 MB
    short* wPackC = (short*)alloc((size_t)2 * 39 * 912 * 8 * 2);
    short* wPackA = (short*)alloc((size_t)6 * 40 * 608 * 8 * 2);   // 2.33 MB
    short* Actx   = (short*)alloc((size_t)5080 * KP * 2);
    float* hout   = (float*)alloc((size_t)2 * NQ * KEFF * 300 * 4);
    float* membank= (float*)alloc((size_t)NQ * KEFF * 300 * 4);
    short* mrkq   = (short*)alloc((size_t)5080 * KP * 2);
    float* mpool  = (float*)alloc((size_t)NN * 600 * 4);
    float* uu     = (float*)alloc((size_t)NN * 300 * 4);
    float* query  = (float*)alloc((size_t)NQ * 300 * 4);
    float* scores = (float*)alloc((size_t)NQ * KEFF * 4);
    float* hbuf   = (float*)alloc((size_t)2 * NQ * 300 * 4);
    float* xgr = giU;   // giU dead after k_utt_scan
    float* xgw = giC;   // giC dead after k_ctx_scan

    const int RKQ = NQ * KEFF;  // 5080

    // 0) weight conversions / packing
    k_conv320<<<dim3(1800), dim3(320), 0, stream>>>(uWih, wUihB);
    k_conv320<<<dim3(1800), dim3(320), 0, stream>>>(cWih, wCihB);
    k_conv320<<<dim3(1800), dim3(320), 0, stream>>>(aWr_w, wArB);
    k_conv320<<<dim3(1800), dim3(320), 0, stream>>>(aW_w, wAwB);
    k_pack_gru<<<dim3((2 * 39 * 900 + 255) / 256), dim3(256), 0, stream>>>(uWhh, wPackU);
    k_pack_gru<<<dim3((2 * 39 * 900 + 255) / 256), dim3(256), 0, stream>>>(cWhh, wPackC);
    k_pack_att<<<dim3((6 * 40 * 600 + 255) / 256), dim3(256), 0, stream>>>(aUr_w, aU_w, wPackA);

    // 1) gather, 2) utt input-gate GEMM (MFMA), 3) utt scan + maxpool
    k_gather_bf16<<<dim3(LL * NN), dim3(320), 0, stream>>>(emb, ids, A_utt);
    k_mgemm<<<dim3(15, 64), dim3(256), 0, stream>>>(A_utt, wUihB, ubih, giU, 8192, 1800);
    k_utt_scan<<<dim3(NN, 2), dim3(960), 0, stream>>>(wPackU, ubhh, giU, lens, mpool);
    // 4) u = tanh(maxpool @ lin_w.T + lin_b)
    k_gemm<<<dim3(3, 1), dim3(256), 0, stream>>>(mpool, linw, linb, uu, NN, 300, 600, 1);
    // 5) query init + ctx rows
    k_init_query<<<dim3(NQ), dim3(128), 0, stream>>>(uu, query);
    k_build_ctxA<<<dim3(RKQ), dim3(320), 0, stream>>>(uu, Actx);
    // 6) ctx input-gate GEMM + ctx scan + combine
    k_mgemm<<<dim3(15, 40), dim3(256), 0, stream>>>(Actx, wCihB, cbih, giC, RKQ, 1800);
    k_ctx_scan<<<dim3(NQ, 2), dim3(960), 0, stream>>>(wPackC, cbhh, giC, hout);
    k_combine<<<dim3(RKQ), dim3(320), 0, stream>>>(uu, hout, membank, mrkq);
    // 7) attention x-projections (all hops/dirs)
    k_mgemm<<<dim3(15, 40), dim3(256), 0, stream>>>(mrkq, wArB, aWr_b, xgr, RKQ, 1800);
    k_mgemm<<<dim3(15, 40), dim3(256), 0, stream>>>(mrkq, wAwB, aW_b, xgw, RKQ, 1800);
    // 8) hops
    for (int hop = 0; hop < 3; ++hop) {
        k_score<<<dim3(NQ), dim3(64), 0, stream>>>(query, membank, scores);
        k_att_scan<<<dim3(NQ, 2), dim3(640), 0, stream>>>(wPackA, aUr_b, aU_b,
                                                          xgr, xgw, scores, hbuf, hop);
        k_qupd<<<dim3(NQ), dim3(128), 0, stream>>>(query, hbuf);
    }
    // 9) classifier
    k_cls<<<dim3(NN), dim3(64), 0, stream>>>(uu, query, clsw, clsb, out);
}